// Round 4
// baseline (1234.130 us; speedup 1.0000x reference)
//
#include <hip/hip_runtime.h>

typedef unsigned short u16;
typedef unsigned int   u32;

#define N_NODES  16384
#define N_EDGES  65536
#define N_GRAPHS 64

// ---------- helpers ----------
__device__ __forceinline__ float bf(u16 u) { return __uint_as_float(((u32)u) << 16); }
__device__ __forceinline__ u16 fb(float f) {
    u32 b = __float_as_uint(f);
    b += 0x7FFFu + ((b >> 16) & 1u);   // round-to-nearest-even
    return (u16)(b >> 16);
}
__device__ __forceinline__ float silu_f(float x) { return x / (1.f + __expf(-x)); }

// ---------- zero ----------
__global__ void k_zero(float* p, int n) {
    int i = blockIdx.x * 256 + threadIdx.x;
    if (i < n) p[i] = 0.f;
}

// ---------- input dtype detector (flag=1 => bf16 inputs; f32 gives flag=0) ----------
__global__ void k_detect(const void* x, int* flag) {
    __shared__ int f;
    if (threadIdx.x == 0) f = 0;
    __syncthreads();
    const u16* p = (const u16*)x;
    for (int i = threadIdx.x; i < 4096; i += 256)
        if (p[i] == 0x3F80u && (i & 1) == 0) f = 1;
    __syncthreads();
    if (threadIdx.x == 0) *flag = f;
}

// ---------- convert 12 weight arrays to canonical bf16 copies ----------
struct CvtArgs { const void* src[12]; int n[12]; };
__global__ void k_convert(CvtArgs a, u16* dst, const int* flag) {
    int fl = *flag;
    size_t base = 0;
    int stride = gridDim.x * 256;
    for (int q = 0; q < 12; q++) {
        int n = a.n[q];
        if (fl) {
            const u16* s = (const u16*)a.src[q];
            for (int i = blockIdx.x * 256 + threadIdx.x; i < n; i += stride)
                dst[base + i] = s[i];
        } else {
            const float* s = (const float*)a.src[q];
            for (int i = blockIdx.x * 256 + threadIdx.x; i < n; i += stride)
                dst[base + i] = fb(s[i]);
        }
        base += n;
    }
}

// ---------- node prep: species + embedding ----------
__global__ __launch_bounds__(128) void k_prep_nodes(const void* x, const u16* Wemb,
                                                    float* nf, int* species, const int* flag) {
    int n = blockIdx.x, k = threadIdx.x;
    __shared__ int sps;
    if (k == 0) {
        int sp = 0;
        if (*flag) {
            const u16* xp = (const u16*)x;
            for (int z = 0; z < 10; z++)
                if (bf(xp[n * 10 + z]) > 0.5f) { sp = z; break; }
        } else {
            const float* xp = (const float*)x;
            for (int z = 0; z < 10; z++)
                if (xp[n * 10 + z] > 0.5f) { sp = z; break; }
        }
        sps = sp;
        species[n] = sp;
    }
    __syncthreads();
    nf[n * 128 + k] = bf(Wemb[sps * 128 + k]) * 0.31622776601683794f; // 1/sqrt(10)
}

// ---------- edge prep: SH + bessel + histogram ----------
__global__ __launch_bounds__(256) void k_prep_edges(const int* eidx, const void* pos,
                                                    float* esh, float* ef, int* hist,
                                                    const int* flag) {
    int e = blockIdx.x * 256 + threadIdx.x;
    int j = eidx[e], i = eidx[N_EDGES + e];
    float vx, vy, vz;
    if (*flag) {
        const u16* p = (const u16*)pos;
        vx = bf(p[j * 3 + 0]) - bf(p[i * 3 + 0]);
        vy = bf(p[j * 3 + 1]) - bf(p[i * 3 + 1]);
        vz = bf(p[j * 3 + 2]) - bf(p[i * 3 + 2]);
    } else {
        const float* p = (const float*)pos;
        vx = p[j * 3 + 0] - p[i * 3 + 0];
        vy = p[j * 3 + 1] - p[i * 3 + 1];
        vz = p[j * 3 + 2] - p[i * 3 + 2];
    }
    float r = sqrtf(vx * vx + vy * vy + vz * vz + 1e-12f);
    float rinv = 1.f / r;
    float X = vx * rinv, Y = vy * rinv, Z = vz * rinv;
    float x2 = X * X, y2 = Y * Y, z2 = Z * Z;
    const float s3 = 1.7320508075688772f, s15 = 3.872983346207417f, s5 = 2.23606797749979f;
    const float s35_8 = 2.091650066335189f, s105 = 10.246950765959598f;
    const float s21_8 = 1.6201851746019651f, s7 = 2.6457513110645907f;
    float Yh[16];
    Yh[0] = 1.f; Yh[1] = s3 * X; Yh[2] = s3 * Y; Yh[3] = s3 * Z;
    Yh[4] = s15 * X * Y; Yh[5] = s15 * Y * Z; Yh[6] = 0.5f * s5 * (3.f * z2 - 1.f);
    Yh[7] = s15 * X * Z; Yh[8] = 0.5f * s15 * (x2 - y2);
    Yh[9] = s35_8 * Y * (3.f * x2 - y2); Yh[10] = s105 * X * Y * Z;
    Yh[11] = s21_8 * Y * (5.f * z2 - 1.f); Yh[12] = 0.5f * s7 * Z * (5.f * z2 - 3.f);
    Yh[13] = s21_8 * X * (5.f * z2 - 1.f); Yh[14] = 0.5f * s105 * Z * (x2 - y2);
    Yh[15] = s35_8 * X * (x2 - 3.f * y2);
#pragma unroll
    for (int m = 0; m < 16; m++) esh[e * 16 + m] = Yh[m];

    float u = r * 0.2f;
    float fc = 0.f;
    if (u < 1.f) {
        float u2 = u * u, u4 = u2 * u2, u5 = u4 * u, u6 = u5 * u, u7 = u6 * u;
        fc = 1.f - 21.f * u5 + 35.f * u6 - 15.f * u7;
    }
    const float pref = 0.6324555320336759f; // sqrt(2/5)
#pragma unroll
    for (int nn = 1; nn <= 8; nn++)
        ef[e * 8 + nn - 1] = pref * sinf((float)nn * 3.14159265358979323846f * u) * rinv * fc;

    atomicAdd(&hist[i], 1);
}

// ---------- exclusive scan of 16384 counts ----------
__global__ __launch_bounds__(1024) void k_scan(const int* hist, int* offs, int* cursor) {
    __shared__ int part[1024];
    int t = threadIdx.x;
    int base = t * 16;
    int v[16]; int s = 0;
#pragma unroll
    for (int q = 0; q < 16; q++) { v[q] = hist[base + q]; s += v[q]; }
    part[t] = s;
    __syncthreads();
    for (int d = 1; d < 1024; d <<= 1) {
        int add = (t >= d) ? part[t - d] : 0;
        __syncthreads();
        part[t] += add;
        __syncthreads();
    }
    int run = part[t] - s; // exclusive
#pragma unroll
    for (int q = 0; q < 16; q++) { offs[base + q] = run; cursor[base + q] = run; run += v[q]; }
    if (t == 1023) offs[16384] = run;
}

// ---------- counting-sort scatter ----------
__global__ __launch_bounds__(256) void k_sort(const int* eidx, int* cursor, int* sorted) {
    int e = blockIdx.x * 256 + threadIdx.x;
    int i = eidx[N_EDGES + e];
    int p = atomicAdd(&cursor[i], 1);
    sorted[p] = e;
}

// ---------- up + skip-connection matvecs (up stored bf16) ----------
__global__ __launch_bounds__(128) void k_up_sc(int t, const float* nf, const int* species,
                                               const u16* Wup, const u16* Wskip,
                                               u16* up, float* sc) {
    int n = blockIdx.x, k = threadIdx.x;
    __shared__ float nfs[128];
    nfs[k] = nf[n * 128 + k];
    __syncthreads();
    int sp = species[n];
    const u16* wu = Wup + (size_t)t * 16384;
    const u16* ws = Wskip + ((size_t)t * 10 + sp) * 16384;
    float au = 0.f, av = 0.f;
#pragma unroll 4
    for (int kk = 0; kk < 128; kk++) {
        float v = nfs[kk];
        au += v * bf(wu[kk * 128 + k]);
        av += v * bf(ws[kk * 128 + k]);
    }
    up[n * 128 + k] = fb(au * 0.08838834764831845f);   // 1/sqrt(128)
    sc[n * 128 + k] = av * 0.027950849718747373f;      // 1/sqrt(1280)
}

// ---------- radial MLP: 8 -> 64 -> 64 -> 64 -> 512, 32 edges/block ----------
__global__ __launch_bounds__(256) void k_radial(int t, const float* ef,
                                                const u16* Wr0, const u16* Wr1,
                                                const u16* Wr2, const u16* Wr3, u16* tpw) {
    __shared__ float efs[8][32];
    __shared__ float hA[64][32];
    __shared__ float hB[64][32];
    __shared__ u16 outs[32 * 516];
    int tid = threadIdx.x;
    int eb = blockIdx.x * 32;
    { int e0 = tid >> 3, b0 = tid & 7; efs[b0][e0] = ef[(eb + e0) * 8 + b0]; }
    __syncthreads();
    int e = tid & 31, og = tid >> 5;
    int o0 = og * 8;
    const u16* w0p = Wr0 + t * 512;
    const u16* w1p = Wr1 + t * 4096;
    const u16* w2p = Wr2 + t * 4096;
    const u16* w3p = Wr3 + (size_t)t * 32768;
    float acc[8];

    // L0 (K=8)
#pragma unroll
    for (int q = 0; q < 8; q++) acc[q] = 0.f;
    for (int b = 0; b < 8; b++) {
        float v = efs[b][e];
        const u16* wp = w0p + b * 64 + o0;
        ushort4 wa = *(const ushort4*)wp, wb = *(const ushort4*)(wp + 4);
        acc[0] += v * bf(wa.x); acc[1] += v * bf(wa.y); acc[2] += v * bf(wa.z); acc[3] += v * bf(wa.w);
        acc[4] += v * bf(wb.x); acc[5] += v * bf(wb.y); acc[6] += v * bf(wb.z); acc[7] += v * bf(wb.w);
    }
#pragma unroll
    for (int q = 0; q < 8; q++) hA[o0 + q][e] = silu_f(acc[q] * 0.35355339059327373f);
    __syncthreads();

    // L1 (K=64)
#pragma unroll
    for (int q = 0; q < 8; q++) acc[q] = 0.f;
    for (int kk = 0; kk < 64; kk++) {
        float v = hA[kk][e];
        const u16* wp = w1p + kk * 64 + o0;
        ushort4 wa = *(const ushort4*)wp, wb = *(const ushort4*)(wp + 4);
        acc[0] += v * bf(wa.x); acc[1] += v * bf(wa.y); acc[2] += v * bf(wa.z); acc[3] += v * bf(wa.w);
        acc[4] += v * bf(wb.x); acc[5] += v * bf(wb.y); acc[6] += v * bf(wb.z); acc[7] += v * bf(wb.w);
    }
#pragma unroll
    for (int q = 0; q < 8; q++) hB[o0 + q][e] = silu_f(acc[q] * 0.125f);
    __syncthreads();

    // L2 (K=64)
#pragma unroll
    for (int q = 0; q < 8; q++) acc[q] = 0.f;
    for (int kk = 0; kk < 64; kk++) {
        float v = hB[kk][e];
        const u16* wp = w2p + kk * 64 + o0;
        ushort4 wa = *(const ushort4*)wp, wb = *(const ushort4*)(wp + 4);
        acc[0] += v * bf(wa.x); acc[1] += v * bf(wa.y); acc[2] += v * bf(wa.z); acc[3] += v * bf(wa.w);
        acc[4] += v * bf(wb.x); acc[5] += v * bf(wb.y); acc[6] += v * bf(wb.z); acc[7] += v * bf(wb.w);
    }
    __syncthreads();
#pragma unroll
    for (int q = 0; q < 8; q++) hA[o0 + q][e] = silu_f(acc[q] * 0.125f);
    __syncthreads();

    // L3 (K=64, 512 outs), no activation
    for (int pass = 0; pass < 8; pass++) {
        int oo = pass * 64 + o0;
#pragma unroll
        for (int q = 0; q < 8; q++) acc[q] = 0.f;
        for (int kk = 0; kk < 64; kk++) {
            float v = hA[kk][e];
            const u16* wp = w3p + kk * 512 + oo;
            ushort4 wa = *(const ushort4*)wp, wb = *(const ushort4*)(wp + 4);
            acc[0] += v * bf(wa.x); acc[1] += v * bf(wa.y); acc[2] += v * bf(wa.z); acc[3] += v * bf(wa.w);
            acc[4] += v * bf(wb.x); acc[5] += v * bf(wb.y); acc[6] += v * bf(wb.z); acc[7] += v * bf(wb.w);
        }
#pragma unroll
        for (int q = 0; q < 8; q++) outs[e * 516 + oo + q] = fb(acc[q] * 0.125f);
    }
    __syncthreads();
    for (int p = 0; p < 64; p++) {
        int flat = p * 256 + tid;
        int ee = flat >> 9, o = flat & 511;
        tpw[(size_t)(eb + ee) * 512 + o] = outs[ee * 516 + o];
    }
}

// ---------- fused: scatter -> A-einsum -> invariants -> product -> prodlin ----------
// 8 nodes/block, 256 threads: 32 threads per node, each owns 4 channels (k4..k4+3).
__global__ __launch_bounds__(256) void k_msgAb(int t, const int* offs, const int* sorted,
                                               const int* eidx, const float* esh,
                                               const u16* up, const u16* tpw,
                                               const u16* Wlin, const int* species,
                                               const u16* Wp1, const u16* Wp2, const u16* Wp3,
                                               const u16* Wpl, const float* sc, float* nf) {
    __shared__ u16 smem_w[16384];   // 32 KB: W_lin[l] staging; later b (fp32, 4 KB)
    __shared__ u16 smem_m[16384];   // 32 KB: msg tile (8 nodes x 16 m x 128 k bf16); later Wpl
    const int LM[16] = {0,1,1,1,2,2,2,2,2,3,3,3,3,3,3,3};
    int tid = threadIdx.x;
    int nsub = tid >> 5;          // 0..7
    int kq = tid & 31;
    int k4 = kq * 4;
    int n = blockIdx.x * 8 + nsub;

    // ---- phase 1: message accumulation (registers) ----
    float acc[16][4];
#pragma unroll
    for (int m = 0; m < 16; m++)
#pragma unroll
        for (int q = 0; q < 4; q++) acc[m][q] = 0.f;
    int s = offs[n], e1 = offs[n + 1];
    for (int idx = s; idx < e1; idx++) {
        int e = sorted[idx];
        int j = eidx[e];
        ushort4 uu = *(const ushort4*)(up + (size_t)j * 128 + k4);
        float u0 = bf(uu.x), u1 = bf(uu.y), u2 = bf(uu.z), u3 = bf(uu.w);
        float4 sA = *(const float4*)(esh + (size_t)e * 16);
        float4 sB = *(const float4*)(esh + (size_t)e * 16 + 4);
        float4 sC = *(const float4*)(esh + (size_t)e * 16 + 8);
        float4 sD = *(const float4*)(esh + (size_t)e * 16 + 12);
        float sh[16] = {sA.x, sA.y, sA.z, sA.w, sB.x, sB.y, sB.z, sB.w,
                        sC.x, sC.y, sC.z, sC.w, sD.x, sD.y, sD.z, sD.w};
        float p[4][4];
#pragma unroll
        for (int l = 0; l < 4; l++) {
            ushort4 tp = *(const ushort4*)(tpw + (size_t)e * 512 + l * 128 + k4);
            p[l][0] = u0 * bf(tp.x); p[l][1] = u1 * bf(tp.y);
            p[l][2] = u2 * bf(tp.z); p[l][3] = u3 * bf(tp.w);
        }
#pragma unroll
        for (int m = 0; m < 16; m++) {
            int l = LM[m];
            acc[m][0] += sh[m] * p[l][0]; acc[m][1] += sh[m] * p[l][1];
            acc[m][2] += sh[m] * p[l][2]; acc[m][3] += sh[m] * p[l][3];
        }
    }
    // msg = acc/10 -> LDS bf16
#pragma unroll
    for (int m = 0; m < 16; m++) {
        ushort4 o;
        o.x = fb(acc[m][0] * 0.1f); o.y = fb(acc[m][1] * 0.1f);
        o.z = fb(acc[m][2] * 0.1f); o.w = fb(acc[m][3] * 0.1f);
        *(ushort4*)&smem_m[nsub * 2048 + m * 128 + k4] = o;
    }
    __syncthreads();

    // ---- phase 2: A = msg @ W_lin[l] / sqrt(128); inv2, A0 in registers ----
    const float sAc = 0.08838834764831845f;
    float inv2[4][4];
#pragma unroll
    for (int l = 0; l < 4; l++)
#pragma unroll
        for (int q = 0; q < 4; q++) inv2[l][q] = 0.f;
    float A0[4] = {0.f, 0.f, 0.f, 0.f};
    const int ms_[4] = {0, 1, 4, 9}, me_[4] = {1, 4, 9, 16};
    for (int l = 0; l < 4; l++) {
        __syncthreads();   // protect previous l's smem_w reads
        const u16* wg = Wlin + ((size_t)t * 4 + l) * 16384;
        for (int p = 0; p < 16; p++)
            ((ushort4*)smem_w)[p * 256 + tid] = ((const ushort4*)wg)[p * 256 + tid];
        __syncthreads();
        for (int m = ms_[l]; m < me_[l]; m++) {
            float a0 = 0.f, a1 = 0.f, a2 = 0.f, a3 = 0.f;
            const u16* mrow = &smem_m[nsub * 2048 + m * 128];
            for (int kk = 0; kk < 128; kk += 4) {
                ushort4 mv = *(const ushort4*)&mrow[kk];
                float m0 = bf(mv.x), m1 = bf(mv.y), m2 = bf(mv.z), m3 = bf(mv.w);
                ushort4 w0 = *(const ushort4*)&smem_w[(kk + 0) * 128 + k4];
                ushort4 w1 = *(const ushort4*)&smem_w[(kk + 1) * 128 + k4];
                ushort4 w2 = *(const ushort4*)&smem_w[(kk + 2) * 128 + k4];
                ushort4 w3 = *(const ushort4*)&smem_w[(kk + 3) * 128 + k4];
                a0 += m0 * bf(w0.x) + m1 * bf(w1.x) + m2 * bf(w2.x) + m3 * bf(w3.x);
                a1 += m0 * bf(w0.y) + m1 * bf(w1.y) + m2 * bf(w2.y) + m3 * bf(w3.y);
                a2 += m0 * bf(w0.z) + m1 * bf(w1.z) + m2 * bf(w2.z) + m3 * bf(w3.z);
                a3 += m0 * bf(w0.w) + m1 * bf(w1.w) + m2 * bf(w2.w) + m3 * bf(w3.w);
            }
            a0 *= sAc; a1 *= sAc; a2 *= sAc; a3 *= sAc;
            if (m == 0) { A0[0] = a0; A0[1] = a1; A0[2] = a2; A0[3] = a3; }
            inv2[l][0] += a0 * a0; inv2[l][1] += a1 * a1;
            inv2[l][2] += a2 * a2; inv2[l][3] += a3 * a3;
        }
    }

    // ---- phase 3: b = w1*A0 + w2.inv2 + (w3.inv2)*A0 ----
    int sp = species[n];
    ushort4 w1v = *(const ushort4*)(Wp1 + ((size_t)t * 10 + sp) * 128 + k4);
    float w1q[4] = {bf(w1v.x), bf(w1v.y), bf(w1v.z), bf(w1v.w)};
    float s2[4] = {0.f, 0.f, 0.f, 0.f}, s3[4] = {0.f, 0.f, 0.f, 0.f};
#pragma unroll
    for (int l = 0; l < 4; l++) {
        ushort4 w2v = *(const ushort4*)(Wp2 + (((size_t)t * 10 + sp) * 4 + l) * 128 + k4);
        ushort4 w3v = *(const ushort4*)(Wp3 + (((size_t)t * 10 + sp) * 4 + l) * 128 + k4);
        s2[0] += bf(w2v.x) * inv2[l][0]; s2[1] += bf(w2v.y) * inv2[l][1];
        s2[2] += bf(w2v.z) * inv2[l][2]; s2[3] += bf(w2v.w) * inv2[l][3];
        s3[0] += bf(w3v.x) * inv2[l][0]; s3[1] += bf(w3v.y) * inv2[l][1];
        s3[2] += bf(w3v.z) * inv2[l][2]; s3[3] += bf(w3v.w) * inv2[l][3];
    }
    float bq[4];
#pragma unroll
    for (int q = 0; q < 4; q++) bq[q] = w1q[q] * A0[q] + s2[q] + s3[q] * A0[q];

    __syncthreads();   // all smem_w / smem_m reads of phase 2 done
    // b -> smem_w (fp32); Wpl -> smem_m
    float* bl = (float*)smem_w;
#pragma unroll
    for (int q = 0; q < 4; q++) bl[nsub * 128 + k4 + q] = bq[q];
    {
        const u16* wg = Wpl + (size_t)t * 16384;
        for (int p = 0; p < 16; p++)
            ((ushort4*)smem_m)[p * 256 + tid] = ((const ushort4*)wg)[p * 256 + tid];
    }
    __syncthreads();

    // ---- phase 4: nf = b @ Wpl / sqrt(128) + sc ----
    float o0 = 0.f, o1 = 0.f, o2 = 0.f, o3 = 0.f;
    for (int kk = 0; kk < 128; kk++) {
        float bv = bl[nsub * 128 + kk];
        ushort4 w = *(const ushort4*)&smem_m[kk * 128 + k4];
        o0 += bv * bf(w.x); o1 += bv * bf(w.y); o2 += bv * bf(w.z); o3 += bv * bf(w.w);
    }
    const float* scp = sc + (size_t)n * 128 + k4;
    float* nfp = nf + (size_t)n * 128 + k4;
    nfp[0] = o0 * sAc + scp[0];
    nfp[1] = o1 * sAc + scp[1];
    nfp[2] = o2 * sAc + scp[2];
    nfp[3] = o3 * sAc + scp[3];
}

// ---------- graph readout ----------
__global__ __launch_bounds__(128) void k_reduce(const float* nf, const int* batch,
                                                float* env, float* cnt) {
    int k = threadIdx.x;
    int n0 = blockIdx.x * 128;
    float run = 0.f;
    int gp = batch[n0];
    for (int nn = 0; nn < 128; nn++) {
        int n = n0 + nn;
        int g = batch[n];
        if (g != gp) { atomicAdd(&env[gp * 128 + k], run); run = 0.f; gp = g; }
        run += nf[n * 128 + k];
    }
    atomicAdd(&env[gp * 128 + k], run);
    if (k == 0) {
        float c = 0.f;
        int g2 = batch[n0];
        for (int nn = 0; nn < 128; nn++) {
            int g = batch[n0 + nn];
            if (g != g2) { atomicAdd(&cnt[g2], c); c = 0.f; g2 = g; }
            c += 1.f;
        }
        atomicAdd(&cnt[g2], c);
    }
}

// ---------- final: OUTPUT IS FLOAT32 (reference returns jnp.float32) ----------
__global__ void k_final(const float* env, const float* cnt, float* out) {
    int i = blockIdx.x * 256 + threadIdx.x;
    if (i < N_GRAPHS * 128) out[i] = env[i] / fmaxf(cnt[i >> 7], 1.f);
}

// ---------- launch ----------
extern "C" void kernel_launch(void* const* d_in, const int* in_sizes, int n_in,
                              void* d_out, int out_size, void* d_ws, size_t ws_size,
                              hipStream_t stream) {
    (void)in_sizes; (void)n_in; (void)out_size; (void)ws_size;
    const void* x    = d_in[0];
    const void* pos  = d_in[1];
    const int* eidx  = (const int*)d_in[14];
    const int* batch = (const int*)d_in[15];

    char* base = (char*)d_ws;
    size_t cur = 0;
    auto alloc = [&](size_t bytes) -> void* {
        void* p = base + cur;
        cur = (cur + bytes + 255) & ~(size_t)255;
        return p;
    };
    // small/critical buffers FIRST; big buffers LAST
    int*   flag    = (int*)alloc(4);
    u16*   cvt     = (u16*)alloc((size_t)631552 * 2);         // canonical bf16 weights
    int*   species = (int*)alloc((size_t)N_NODES * 4);
    int*   hist    = (int*)alloc((size_t)N_NODES * 4);
    int*   offs    = (int*)alloc((size_t)(N_NODES + 1) * 4);
    int*   cursor  = (int*)alloc((size_t)N_NODES * 4);
    int*   sorted  = (int*)alloc((size_t)N_EDGES * 4);
    float* env     = (float*)alloc((size_t)N_GRAPHS * 128 * 4);
    float* cnt     = (float*)alloc((size_t)N_GRAPHS * 4);
    float* nf      = (float*)alloc((size_t)N_NODES * 128 * 4);
    u16*   up      = (u16*)alloc((size_t)N_NODES * 128 * 2);
    float* sc      = (float*)alloc((size_t)N_NODES * 128 * 4);
    float* ef      = (float*)alloc((size_t)N_EDGES * 8 * 4);
    float* esh     = (float*)alloc((size_t)N_EDGES * 16 * 4);
    u16*   tpw     = (u16*)alloc((size_t)N_EDGES * 512 * 2);
    // total ~92 MB

    static const int cn[12] = {1280, 32768, 1024, 8192, 8192, 65536,
                               131072, 327680, 2560, 10240, 10240, 32768};
    CvtArgs ca;
    size_t off[13]; off[0] = 0;
    for (int q = 0; q < 12; q++) { ca.src[q] = d_in[2 + q]; ca.n[q] = cn[q]; off[q + 1] = off[q] + cn[q]; }
    u16* cWemb = cvt + off[0];
    u16* cWup  = cvt + off[1];
    u16* cWr0  = cvt + off[2];
    u16* cWr1  = cvt + off[3];
    u16* cWr2  = cvt + off[4];
    u16* cWr3  = cvt + off[5];
    u16* cWlin = cvt + off[6];
    u16* cWskip= cvt + off[7];
    u16* cWp1  = cvt + off[8];
    u16* cWp2  = cvt + off[9];
    u16* cWp3  = cvt + off[10];
    u16* cWpl  = cvt + off[11];

    k_detect<<<1, 256, 0, stream>>>(x, flag);
    k_convert<<<256, 256, 0, stream>>>(ca, cvt, flag);
    k_zero<<<64, 256, 0, stream>>>((float*)hist, N_NODES);
    k_zero<<<32, 256, 0, stream>>>(env, N_GRAPHS * 128);
    k_zero<<<1, 256, 0, stream>>>(cnt, N_GRAPHS);
    k_prep_nodes<<<N_NODES, 128, 0, stream>>>(x, cWemb, nf, species, flag);
    k_prep_edges<<<N_EDGES / 256, 256, 0, stream>>>(eidx, pos, esh, ef, hist, flag);
    k_scan<<<1, 1024, 0, stream>>>(hist, offs, cursor);
    k_sort<<<N_EDGES / 256, 256, 0, stream>>>(eidx, cursor, sorted);

    for (int t = 0; t < 2; t++) {
        k_up_sc<<<N_NODES, 128, 0, stream>>>(t, nf, species, cWup, cWskip, up, sc);
        k_radial<<<N_EDGES / 32, 256, 0, stream>>>(t, ef, cWr0, cWr1, cWr2, cWr3, tpw);
        k_msgAb<<<N_NODES / 8, 256, 0, stream>>>(t, offs, sorted, eidx, esh, up, tpw,
                                                 cWlin, species, cWp1, cWp2, cWp3, cWpl, sc, nf);
    }
    k_reduce<<<N_NODES / 128, 128, 0, stream>>>(nf, batch, env, cnt);
    k_final<<<32, 256, 0, stream>>>(env, cnt, (float*)d_out);
}

// Round 5
// 873.228 us; speedup vs baseline: 1.4133x; 1.4133x over previous
//
#include <hip/hip_runtime.h>

typedef unsigned short u16;
typedef unsigned int   u32;
typedef __attribute__((ext_vector_type(8))) short short8;
typedef __attribute__((ext_vector_type(4))) float float4v;

#define N_NODES  16384
#define N_EDGES  65536
#define N_GRAPHS 64

// ---------- helpers ----------
__device__ __forceinline__ float bf(u16 u) { return __uint_as_float(((u32)u) << 16); }
__device__ __forceinline__ u16 fb(float f) {
    u32 b = __float_as_uint(f);
    b += 0x7FFFu + ((b >> 16) & 1u);   // round-to-nearest-even
    return (u16)(b >> 16);
}
__device__ __forceinline__ float silu_f(float x) { return x / (1.f + __expf(-x)); }

// l-grouped msg/A row layout: row = RB[m] + n*RS[m]
// l0: rows 0..16383 | l1: 16384+.. (3/node) | l2: 65536+.. (5/node) | l3: 147456+.. (7/node)
__device__ __constant__ int RBc[16] = {0, 16384,16385,16386, 65536,65537,65538,65539,65540,
                                       147456,147457,147458,147459,147460,147461,147462};
__device__ __constant__ int RSc[16] = {1,3,3,3,5,5,5,5,5,7,7,7,7,7,7,7};

// ---------- zero ----------
__global__ void k_zero(float* p, int n) {
    int i = blockIdx.x * 256 + threadIdx.x;
    if (i < n) p[i] = 0.f;
}

// ---------- input dtype detector (flag=1 => bf16 inputs; f32 gives flag=0) ----------
__global__ void k_detect(const void* x, int* flag) {
    __shared__ int f;
    if (threadIdx.x == 0) f = 0;
    __syncthreads();
    const u16* p = (const u16*)x;
    for (int i = threadIdx.x; i < 4096; i += 256)
        if (p[i] == 0x3F80u && (i & 1) == 0) f = 1;
    __syncthreads();
    if (threadIdx.x == 0) *flag = f;
}

// ---------- convert 12 weight arrays to canonical bf16 copies ----------
// q==6 (W_lin, [8 slab][128 kk][128 n]) is stored TRANSPOSED: [slab][n][kk]
struct CvtArgs { const void* src[12]; int n[12]; };
__global__ void k_convert(CvtArgs a, u16* dst, const int* flag) {
    int fl = *flag;
    size_t base = 0;
    int stride = gridDim.x * 256;
    for (int q = 0; q < 12; q++) {
        int n = a.n[q];
        for (int i = blockIdx.x * 256 + threadIdx.x; i < n; i += stride) {
            u16 v;
            if (fl) v = ((const u16*)a.src[q])[i];
            else    v = fb(((const float*)a.src[q])[i]);
            if (q == 6) {
                int slab = i >> 14, rem = i & 16383, kk = rem >> 7, nn = rem & 127;
                dst[base + slab * 16384 + nn * 128 + kk] = v;
            } else {
                dst[base + i] = v;
            }
        }
        base += n;
    }
}

// ---------- node prep: species + embedding ----------
__global__ __launch_bounds__(128) void k_prep_nodes(const void* x, const u16* Wemb,
                                                    float* nf, int* species, const int* flag) {
    int n = blockIdx.x, k = threadIdx.x;
    __shared__ int sps;
    if (k == 0) {
        int sp = 0;
        if (*flag) {
            const u16* xp = (const u16*)x;
            for (int z = 0; z < 10; z++)
                if (bf(xp[n * 10 + z]) > 0.5f) { sp = z; break; }
        } else {
            const float* xp = (const float*)x;
            for (int z = 0; z < 10; z++)
                if (xp[n * 10 + z] > 0.5f) { sp = z; break; }
        }
        sps = sp;
        species[n] = sp;
    }
    __syncthreads();
    nf[n * 128 + k] = bf(Wemb[sps * 128 + k]) * 0.31622776601683794f; // 1/sqrt(10)
}

// ---------- edge prep: SH + bessel + histogram ----------
__global__ __launch_bounds__(256) void k_prep_edges(const int* eidx, const void* pos,
                                                    float* esh, float* ef, int* hist,
                                                    const int* flag) {
    int e = blockIdx.x * 256 + threadIdx.x;
    int j = eidx[e], i = eidx[N_EDGES + e];
    float vx, vy, vz;
    if (*flag) {
        const u16* p = (const u16*)pos;
        vx = bf(p[j * 3 + 0]) - bf(p[i * 3 + 0]);
        vy = bf(p[j * 3 + 1]) - bf(p[i * 3 + 1]);
        vz = bf(p[j * 3 + 2]) - bf(p[i * 3 + 2]);
    } else {
        const float* p = (const float*)pos;
        vx = p[j * 3 + 0] - p[i * 3 + 0];
        vy = p[j * 3 + 1] - p[i * 3 + 1];
        vz = p[j * 3 + 2] - p[i * 3 + 2];
    }
    float r = sqrtf(vx * vx + vy * vy + vz * vz + 1e-12f);
    float rinv = 1.f / r;
    float X = vx * rinv, Y = vy * rinv, Z = vz * rinv;
    float x2 = X * X, y2 = Y * Y, z2 = Z * Z;
    const float s3 = 1.7320508075688772f, s15 = 3.872983346207417f, s5 = 2.23606797749979f;
    const float s35_8 = 2.091650066335189f, s105 = 10.246950765959598f;
    const float s21_8 = 1.6201851746019651f, s7 = 2.6457513110645907f;
    float Yh[16];
    Yh[0] = 1.f; Yh[1] = s3 * X; Yh[2] = s3 * Y; Yh[3] = s3 * Z;
    Yh[4] = s15 * X * Y; Yh[5] = s15 * Y * Z; Yh[6] = 0.5f * s5 * (3.f * z2 - 1.f);
    Yh[7] = s15 * X * Z; Yh[8] = 0.5f * s15 * (x2 - y2);
    Yh[9] = s35_8 * Y * (3.f * x2 - y2); Yh[10] = s105 * X * Y * Z;
    Yh[11] = s21_8 * Y * (5.f * z2 - 1.f); Yh[12] = 0.5f * s7 * Z * (5.f * z2 - 3.f);
    Yh[13] = s21_8 * X * (5.f * z2 - 1.f); Yh[14] = 0.5f * s105 * Z * (x2 - y2);
    Yh[15] = s35_8 * X * (x2 - 3.f * y2);
#pragma unroll
    for (int m = 0; m < 16; m++) esh[e * 16 + m] = Yh[m];

    float u = r * 0.2f;
    float fc = 0.f;
    if (u < 1.f) {
        float u2 = u * u, u4 = u2 * u2, u5 = u4 * u, u6 = u5 * u, u7 = u6 * u;
        fc = 1.f - 21.f * u5 + 35.f * u6 - 15.f * u7;
    }
    const float pref = 0.6324555320336759f; // sqrt(2/5)
#pragma unroll
    for (int nn = 1; nn <= 8; nn++)
        ef[e * 8 + nn - 1] = pref * sinf((float)nn * 3.14159265358979323846f * u) * rinv * fc;

    atomicAdd(&hist[i], 1);
}

// ---------- exclusive scan of 16384 counts ----------
__global__ __launch_bounds__(1024) void k_scan(const int* hist, int* offs, int* cursor) {
    __shared__ int part[1024];
    int t = threadIdx.x;
    int base = t * 16;
    int v[16]; int s = 0;
#pragma unroll
    for (int q = 0; q < 16; q++) { v[q] = hist[base + q]; s += v[q]; }
    part[t] = s;
    __syncthreads();
    for (int d = 1; d < 1024; d <<= 1) {
        int add = (t >= d) ? part[t - d] : 0;
        __syncthreads();
        part[t] += add;
        __syncthreads();
    }
    int run = part[t] - s; // exclusive
#pragma unroll
    for (int q = 0; q < 16; q++) { offs[base + q] = run; cursor[base + q] = run; run += v[q]; }
    if (t == 1023) offs[16384] = run;
}

// ---------- counting-sort scatter ----------
__global__ __launch_bounds__(256) void k_sort(const int* eidx, int* cursor, int* sorted) {
    int e = blockIdx.x * 256 + threadIdx.x;
    int i = eidx[N_EDGES + e];
    int p = atomicAdd(&cursor[i], 1);
    sorted[p] = e;
}

// ---------- up + skip-connection matvecs (up stored bf16) ----------
__global__ __launch_bounds__(128) void k_up_sc(int t, const float* nf, const int* species,
                                               const u16* Wup, const u16* Wskip,
                                               u16* up, float* sc) {
    int n = blockIdx.x, k = threadIdx.x;
    __shared__ float nfs[128];
    nfs[k] = nf[n * 128 + k];
    __syncthreads();
    int sp = species[n];
    const u16* wu = Wup + (size_t)t * 16384;
    const u16* ws = Wskip + ((size_t)t * 10 + sp) * 16384;
    float au = 0.f, av = 0.f;
#pragma unroll 4
    for (int kk = 0; kk < 128; kk++) {
        float v = nfs[kk];
        au += v * bf(wu[kk * 128 + k]);
        av += v * bf(ws[kk * 128 + k]);
    }
    up[n * 128 + k] = fb(au * 0.08838834764831845f);   // 1/sqrt(128)
    sc[n * 128 + k] = av * 0.027950849718747373f;      // 1/sqrt(1280)
}

// ---------- radial MLP: 8 -> 64 -> 64 -> 64 -> 512, 32 edges/block ----------
__global__ __launch_bounds__(256) void k_radial(int t, const float* ef,
                                                const u16* Wr0, const u16* Wr1,
                                                const u16* Wr2, const u16* Wr3, u16* tpw) {
    __shared__ float efs[8][32];
    __shared__ float hA[64][32];
    __shared__ float hB[64][32];
    __shared__ u16 outs[32 * 516];
    int tid = threadIdx.x;
    int eb = blockIdx.x * 32;
    { int e0 = tid >> 3, b0 = tid & 7; efs[b0][e0] = ef[(eb + e0) * 8 + b0]; }
    __syncthreads();
    int e = tid & 31, og = tid >> 5;
    int o0 = og * 8;
    const u16* w0p = Wr0 + t * 512;
    const u16* w1p = Wr1 + t * 4096;
    const u16* w2p = Wr2 + t * 4096;
    const u16* w3p = Wr3 + (size_t)t * 32768;
    float acc[8];

    // L0 (K=8)
#pragma unroll
    for (int q = 0; q < 8; q++) acc[q] = 0.f;
    for (int b = 0; b < 8; b++) {
        float v = efs[b][e];
        const u16* wp = w0p + b * 64 + o0;
        ushort4 wa = *(const ushort4*)wp, wb = *(const ushort4*)(wp + 4);
        acc[0] += v * bf(wa.x); acc[1] += v * bf(wa.y); acc[2] += v * bf(wa.z); acc[3] += v * bf(wa.w);
        acc[4] += v * bf(wb.x); acc[5] += v * bf(wb.y); acc[6] += v * bf(wb.z); acc[7] += v * bf(wb.w);
    }
#pragma unroll
    for (int q = 0; q < 8; q++) hA[o0 + q][e] = silu_f(acc[q] * 0.35355339059327373f);
    __syncthreads();

    // L1 (K=64)
#pragma unroll
    for (int q = 0; q < 8; q++) acc[q] = 0.f;
    for (int kk = 0; kk < 64; kk++) {
        float v = hA[kk][e];
        const u16* wp = w1p + kk * 64 + o0;
        ushort4 wa = *(const ushort4*)wp, wb = *(const ushort4*)(wp + 4);
        acc[0] += v * bf(wa.x); acc[1] += v * bf(wa.y); acc[2] += v * bf(wa.z); acc[3] += v * bf(wa.w);
        acc[4] += v * bf(wb.x); acc[5] += v * bf(wb.y); acc[6] += v * bf(wb.z); acc[7] += v * bf(wb.w);
    }
#pragma unroll
    for (int q = 0; q < 8; q++) hB[o0 + q][e] = silu_f(acc[q] * 0.125f);
    __syncthreads();

    // L2 (K=64)
#pragma unroll
    for (int q = 0; q < 8; q++) acc[q] = 0.f;
    for (int kk = 0; kk < 64; kk++) {
        float v = hB[kk][e];
        const u16* wp = w2p + kk * 64 + o0;
        ushort4 wa = *(const ushort4*)wp, wb = *(const ushort4*)(wp + 4);
        acc[0] += v * bf(wa.x); acc[1] += v * bf(wa.y); acc[2] += v * bf(wa.z); acc[3] += v * bf(wa.w);
        acc[4] += v * bf(wb.x); acc[5] += v * bf(wb.y); acc[6] += v * bf(wb.z); acc[7] += v * bf(wb.w);
    }
    __syncthreads();
#pragma unroll
    for (int q = 0; q < 8; q++) hA[o0 + q][e] = silu_f(acc[q] * 0.125f);
    __syncthreads();

    // L3 (K=64, 512 outs), no activation
    for (int pass = 0; pass < 8; pass++) {
        int oo = pass * 64 + o0;
#pragma unroll
        for (int q = 0; q < 8; q++) acc[q] = 0.f;
        for (int kk = 0; kk < 64; kk++) {
            float v = hA[kk][e];
            const u16* wp = w3p + kk * 512 + oo;
            ushort4 wa = *(const ushort4*)wp, wb = *(const ushort4*)(wp + 4);
            acc[0] += v * bf(wa.x); acc[1] += v * bf(wa.y); acc[2] += v * bf(wa.z); acc[3] += v * bf(wa.w);
            acc[4] += v * bf(wb.x); acc[5] += v * bf(wb.y); acc[6] += v * bf(wb.z); acc[7] += v * bf(wb.w);
        }
#pragma unroll
        for (int q = 0; q < 8; q++) outs[e * 516 + oo + q] = fb(acc[q] * 0.125f);
    }
    __syncthreads();
    for (int p = 0; p < 64; p++) {
        int flat = p * 256 + tid;
        int ee = flat >> 9, o = flat & 511;
        tpw[(size_t)(eb + ee) * 512 + o] = outs[ee * 516 + o];
    }
}

// ---------- message accumulation -> l-grouped global msg (bf16) ----------
// 8 nodes/block, 256 threads: 32 threads per node, each owns 4 channels.
__global__ __launch_bounds__(256) void k_msg(const int* offs, const int* sorted,
                                             const int* eidx, const float* esh,
                                             const u16* up, const u16* tpw, u16* msgA) {
    const int LM[16] = {0,1,1,1,2,2,2,2,2,3,3,3,3,3,3,3};
    int tid = threadIdx.x;
    int nsub = tid >> 5;
    int kq = tid & 31;
    int k4 = kq * 4;
    int n = blockIdx.x * 8 + nsub;

    float acc[16][4];
#pragma unroll
    for (int m = 0; m < 16; m++)
#pragma unroll
        for (int q = 0; q < 4; q++) acc[m][q] = 0.f;
    int s = offs[n], e1 = offs[n + 1];
    for (int idx = s; idx < e1; idx++) {
        int e = sorted[idx];
        int j = eidx[e];
        ushort4 uu = *(const ushort4*)(up + (size_t)j * 128 + k4);
        float u0 = bf(uu.x), u1 = bf(uu.y), u2 = bf(uu.z), u3 = bf(uu.w);
        float4 sA = *(const float4*)(esh + (size_t)e * 16);
        float4 sB = *(const float4*)(esh + (size_t)e * 16 + 4);
        float4 sC = *(const float4*)(esh + (size_t)e * 16 + 8);
        float4 sD = *(const float4*)(esh + (size_t)e * 16 + 12);
        float sh[16] = {sA.x, sA.y, sA.z, sA.w, sB.x, sB.y, sB.z, sB.w,
                        sC.x, sC.y, sC.z, sC.w, sD.x, sD.y, sD.z, sD.w};
        float p[4][4];
#pragma unroll
        for (int l = 0; l < 4; l++) {
            ushort4 tp = *(const ushort4*)(tpw + (size_t)e * 512 + l * 128 + k4);
            p[l][0] = u0 * bf(tp.x); p[l][1] = u1 * bf(tp.y);
            p[l][2] = u2 * bf(tp.z); p[l][3] = u3 * bf(tp.w);
        }
#pragma unroll
        for (int m = 0; m < 16; m++) {
            int l = LM[m];
            acc[m][0] += sh[m] * p[l][0]; acc[m][1] += sh[m] * p[l][1];
            acc[m][2] += sh[m] * p[l][2]; acc[m][3] += sh[m] * p[l][3];
        }
    }
#pragma unroll
    for (int m = 0; m < 16; m++) {
        int row = RBc[m] + n * RSc[m];
        ushort4 o;
        o.x = fb(acc[m][0] * 0.1f); o.y = fb(acc[m][1] * 0.1f);
        o.z = fb(acc[m][2] * 0.1f); o.w = fb(acc[m][3] * 0.1f);
        *(ushort4*)(msgA + (size_t)row * 128 + k4) = o;
    }
}

// ---------- A = msg @ W_lin[l] / sqrt(128): MFMA GEMM, in-place over msgA ----------
// 64 rows/block, 256 threads (4 waves x 16 rows). WlinT staged in LDS in frag order.
__global__ __launch_bounds__(256) void k_gemmA(int t, u16* msgA, const u16* WlinT) {
    __shared__ u16 wfr[16384];   // 32 KB, fragment-ordered: [(nt*4+ks)*64 + lane]*8
    int b = blockIdx.x;
    int l, rb0;
    if (b < 256)       { l = 0; rb0 = b * 64; }
    else if (b < 1024) { l = 1; rb0 = 16384  + (b - 256)  * 64; }
    else if (b < 2304) { l = 2; rb0 = 65536  + (b - 1024) * 64; }
    else               { l = 3; rb0 = 147456 + (b - 2304) * 64; }
    int tid = threadIdx.x;
    const u16* wg = WlinT + ((size_t)t * 4 + l) * 16384;   // [n][kk]
#pragma unroll
    for (int p = 0; p < 8; p++) {
        int slot = p * 256 + tid;            // (nt, ks, lane)
        int nt = slot >> 8, ks = (slot >> 6) & 3, ln = slot & 63;
        int nn = nt * 16 + (ln & 15), k0 = ks * 32 + (ln >> 4) * 8;
        *(uint4*)&wfr[slot * 8] = *(const uint4*)&wg[nn * 128 + k0];
    }
    __syncthreads();

    int wave = tid >> 6, lane = tid & 63;
    int m16 = lane & 15, quad = lane >> 4;
    int rowa = rb0 + wave * 16 + m16;
    const u16* ap = msgA + (size_t)rowa * 128 + quad * 8;
    short8 afr[4];
#pragma unroll
    for (int ks = 0; ks < 4; ks++) afr[ks] = *(const short8*)(ap + ks * 32);

    float4v acc[8];
#pragma unroll
    for (int nt = 0; nt < 8; nt++) acc[nt] = (float4v){0.f, 0.f, 0.f, 0.f};
#pragma unroll
    for (int nt = 0; nt < 8; nt++)
#pragma unroll
        for (int ks = 0; ks < 4; ks++) {
            short8 bfr = *(const short8*)&wfr[((nt * 4 + ks) * 64 + lane) * 8];
            acc[nt] = __builtin_amdgcn_mfma_f32_16x16x32_bf16(afr[ks], bfr, acc[nt], 0, 0, 0);
        }

    const float sAc = 0.08838834764831845f;
    int rowc = rb0 + wave * 16 + quad * 4;
#pragma unroll
    for (int nt = 0; nt < 8; nt++)
#pragma unroll
        for (int r = 0; r < 4; r++)
            msgA[(size_t)(rowc + r) * 128 + nt * 16 + m16] = fb(acc[nt][r] * sAc);
}

// ---------- invariants + product basis + prodlin + skip ----------
__global__ __launch_bounds__(128) void k_bprod(int t, const u16* Ag, const int* species,
                                               const u16* Wp1, const u16* Wp2, const u16* Wp3,
                                               const u16* Wpl, const float* sc, float* nf) {
    const int LM[16] = {0,1,1,1,2,2,2,2,2,3,3,3,3,3,3,3};
    int n = blockIdx.x, k = threadIdx.x;
    int sp = species[n];
    float Am[16];
#pragma unroll
    for (int m = 0; m < 16; m++)
        Am[m] = bf(Ag[(size_t)(RBc[m] + n * RSc[m]) * 128 + k]);
    float A0 = Am[0];
    float inv2[4] = {0.f, 0.f, 0.f, 0.f};
#pragma unroll
    for (int m = 0; m < 16; m++) inv2[LM[m]] += Am[m] * Am[m];
    float w1 = bf(Wp1[((size_t)t * 10 + sp) * 128 + k]);
    float s2 = 0.f, s3v = 0.f;
#pragma unroll
    for (int l = 0; l < 4; l++) {
        float w2 = bf(Wp2[(((size_t)t * 10 + sp) * 4 + l) * 128 + k]);
        float w3 = bf(Wp3[(((size_t)t * 10 + sp) * 4 + l) * 128 + k]);
        s2 += w2 * inv2[l];
        s3v += w3 * inv2[l];
    }
    float b = w1 * A0 + s2 + s3v * A0;
    __shared__ float bs[128];
    bs[k] = b;
    __syncthreads();
    const u16* wp = Wpl + (size_t)t * 16384;
    float acc = 0.f;
#pragma unroll 4
    for (int kk = 0; kk < 128; kk++) acc += bs[kk] * bf(wp[kk * 128 + k]);
    nf[n * 128 + k] = acc * 0.08838834764831845f + sc[n * 128 + k];
}

// ---------- graph readout ----------
__global__ __launch_bounds__(128) void k_reduce(const float* nf, const int* batch,
                                                float* env, float* cnt) {
    int k = threadIdx.x;
    int n0 = blockIdx.x * 128;
    float run = 0.f;
    int gp = batch[n0];
    for (int nn = 0; nn < 128; nn++) {
        int n = n0 + nn;
        int g = batch[n];
        if (g != gp) { atomicAdd(&env[gp * 128 + k], run); run = 0.f; gp = g; }
        run += nf[n * 128 + k];
    }
    atomicAdd(&env[gp * 128 + k], run);
    if (k == 0) {
        float c = 0.f;
        int g2 = batch[n0];
        for (int nn = 0; nn < 128; nn++) {
            int g = batch[n0 + nn];
            if (g != g2) { atomicAdd(&cnt[g2], c); c = 0.f; g2 = g; }
            c += 1.f;
        }
        atomicAdd(&cnt[g2], c);
    }
}

// ---------- final: output float32 ----------
__global__ void k_final(const float* env, const float* cnt, float* out) {
    int i = blockIdx.x * 256 + threadIdx.x;
    if (i < N_GRAPHS * 128) out[i] = env[i] / fmaxf(cnt[i >> 7], 1.f);
}

// ---------- launch ----------
extern "C" void kernel_launch(void* const* d_in, const int* in_sizes, int n_in,
                              void* d_out, int out_size, void* d_ws, size_t ws_size,
                              hipStream_t stream) {
    (void)in_sizes; (void)n_in; (void)out_size; (void)ws_size;
    const void* x    = d_in[0];
    const void* pos  = d_in[1];
    const int* eidx  = (const int*)d_in[14];
    const int* batch = (const int*)d_in[15];

    char* base = (char*)d_ws;
    size_t cur = 0;
    auto alloc = [&](size_t bytes) -> void* {
        void* p = base + cur;
        cur = (cur + bytes + 255) & ~(size_t)255;
        return p;
    };
    int*   flag    = (int*)alloc(4);
    u16*   cvt     = (u16*)alloc((size_t)631552 * 2);         // canonical bf16 weights
    int*   species = (int*)alloc((size_t)N_NODES * 4);
    int*   hist    = (int*)alloc((size_t)N_NODES * 4);
    int*   offs    = (int*)alloc((size_t)(N_NODES + 1) * 4);
    int*   cursor  = (int*)alloc((size_t)N_NODES * 4);
    int*   sorted  = (int*)alloc((size_t)N_EDGES * 4);
    float* env     = (float*)alloc((size_t)N_GRAPHS * 128 * 4);
    float* cnt     = (float*)alloc((size_t)N_GRAPHS * 4);
    float* nf      = (float*)alloc((size_t)N_NODES * 128 * 4);
    u16*   up      = (u16*)alloc((size_t)N_NODES * 128 * 2);
    float* sc      = (float*)alloc((size_t)N_NODES * 128 * 4);
    float* ef      = (float*)alloc((size_t)N_EDGES * 8 * 4);
    float* esh     = (float*)alloc((size_t)N_EDGES * 16 * 4);
    u16*   tpw     = (u16*)alloc((size_t)N_EDGES * 512 * 2);  // 64 MB
    u16*   msgA    = (u16*)alloc((size_t)262144 * 128 * 2);   // 64 MB, msg then A in-place
    // total ~156 MB (ws_size >= 168 MB evidenced by r2/r3 bit-identical absmax)

    static const int cn[12] = {1280, 32768, 1024, 8192, 8192, 65536,
                               131072, 327680, 2560, 10240, 10240, 32768};
    CvtArgs ca;
    size_t off[13]; off[0] = 0;
    for (int q = 0; q < 12; q++) { ca.src[q] = d_in[2 + q]; ca.n[q] = cn[q]; off[q + 1] = off[q] + cn[q]; }
    u16* cWemb  = cvt + off[0];
    u16* cWup   = cvt + off[1];
    u16* cWr0   = cvt + off[2];
    u16* cWr1   = cvt + off[3];
    u16* cWr2   = cvt + off[4];
    u16* cWr3   = cvt + off[5];
    u16* cWlinT = cvt + off[6];   // stored transposed [t][l][n][kk]
    u16* cWskip = cvt + off[7];
    u16* cWp1   = cvt + off[8];
    u16* cWp2   = cvt + off[9];
    u16* cWp3   = cvt + off[10];
    u16* cWpl   = cvt + off[11];

    k_detect<<<1, 256, 0, stream>>>(x, flag);
    k_convert<<<256, 256, 0, stream>>>(ca, cvt, flag);
    k_zero<<<64, 256, 0, stream>>>((float*)hist, N_NODES);
    k_zero<<<32, 256, 0, stream>>>(env, N_GRAPHS * 128);
    k_zero<<<1, 256, 0, stream>>>(cnt, N_GRAPHS);
    k_prep_nodes<<<N_NODES, 128, 0, stream>>>(x, cWemb, nf, species, flag);
    k_prep_edges<<<N_EDGES / 256, 256, 0, stream>>>(eidx, pos, esh, ef, hist, flag);
    k_scan<<<1, 1024, 0, stream>>>(hist, offs, cursor);
    k_sort<<<N_EDGES / 256, 256, 0, stream>>>(eidx, cursor, sorted);

    for (int t = 0; t < 2; t++) {
        k_up_sc<<<N_NODES, 128, 0, stream>>>(t, nf, species, cWup, cWskip, up, sc);
        k_radial<<<N_EDGES / 32, 256, 0, stream>>>(t, ef, cWr0, cWr1, cWr2, cWr3, tpw);
        k_msg<<<N_NODES / 8, 256, 0, stream>>>(offs, sorted, eidx, esh, up, tpw, msgA);
        k_gemmA<<<4096, 256, 0, stream>>>(t, msgA, cWlinT);
        k_bprod<<<N_NODES, 128, 0, stream>>>(t, msgA, species, cWp1, cWp2, cWp3, cWpl, sc, nf);
    }
    k_reduce<<<N_NODES / 128, 128, 0, stream>>>(nf, batch, env, cnt);
    k_final<<<32, 256, 0, stream>>>(env, cnt, (float*)d_out);
}

// Round 6
// 642.108 us; speedup vs baseline: 1.9220x; 1.3599x over previous
//
#include <hip/hip_runtime.h>

typedef unsigned short u16;
typedef unsigned int   u32;
typedef __attribute__((ext_vector_type(8))) short short8;
typedef __attribute__((ext_vector_type(4))) float float4v;

#define N_NODES  16384
#define N_EDGES  65536
#define N_GRAPHS 64

// ---------- helpers ----------
__device__ __forceinline__ float bf(u16 u) { return __uint_as_float(((u32)u) << 16); }
__device__ __forceinline__ u16 fb(float f) {
    u32 b = __float_as_uint(f);
    b += 0x7FFFu + ((b >> 16) & 1u);   // round-to-nearest-even
    return (u16)(b >> 16);
}
__device__ __forceinline__ float silu_f(float x) { return x / (1.f + __expf(-x)); }

// l-grouped msg/A row layout: row = RB[m] + n*RS[m]
__device__ __constant__ int RBc[16] = {0, 16384,16385,16386, 65536,65537,65538,65539,65540,
                                       147456,147457,147458,147459,147460,147461,147462};
__device__ __constant__ int RSc[16] = {1,3,3,3,5,5,5,5,5,7,7,7,7,7,7,7};

// ---------- zero ----------
__global__ void k_zero(float* p, int n) {
    int i = blockIdx.x * 256 + threadIdx.x;
    if (i < n) p[i] = 0.f;
}

// ---------- input dtype detector (flag=1 => bf16 inputs; f32 gives flag=0) ----------
__global__ void k_detect(const void* x, int* flag) {
    __shared__ int f;
    if (threadIdx.x == 0) f = 0;
    __syncthreads();
    const u16* p = (const u16*)x;
    for (int i = threadIdx.x; i < 4096; i += 256)
        if (p[i] == 0x3F80u && (i & 1) == 0) f = 1;
    __syncthreads();
    if (threadIdx.x == 0) *flag = f;
}

// ---------- convert 12 weight arrays to canonical bf16 copies ----------
// q==6 (W_lin): stored transposed [slab][n][kk]
// q==3/4 (Wr1/Wr2, [2][64][64]): stored transposed [t][n][k]
// q==5 (Wr3, [2][64][512]):      stored transposed [t][n][k]
struct CvtArgs { const void* src[12]; int n[12]; };
__global__ void k_convert(CvtArgs a, u16* dst, const int* flag) {
    int fl = *flag;
    size_t base = 0;
    int stride = gridDim.x * 256;
    for (int q = 0; q < 12; q++) {
        int n = a.n[q];
        for (int i = blockIdx.x * 256 + threadIdx.x; i < n; i += stride) {
            u16 v;
            if (fl) v = ((const u16*)a.src[q])[i];
            else    v = fb(((const float*)a.src[q])[i]);
            if (q == 6) {
                int slab = i >> 14, rem = i & 16383, kk = rem >> 7, nn = rem & 127;
                dst[base + slab * 16384 + nn * 128 + kk] = v;
            } else if (q == 3 || q == 4) {
                int tq = i >> 12, rem = i & 4095, kk = rem >> 6, nn = rem & 63;
                dst[base + tq * 4096 + nn * 64 + kk] = v;
            } else if (q == 5) {
                int tq = i >> 15, rem = i & 32767, kk = rem >> 9, nn = rem & 511;
                dst[base + tq * 32768 + nn * 64 + kk] = v;
            } else {
                dst[base + i] = v;
            }
        }
        base += n;
    }
}

// ---------- node prep: species + embedding ----------
__global__ __launch_bounds__(128) void k_prep_nodes(const void* x, const u16* Wemb,
                                                    float* nf, int* species, const int* flag) {
    int n = blockIdx.x, k = threadIdx.x;
    __shared__ int sps;
    if (k == 0) {
        int sp = 0;
        if (*flag) {
            const u16* xp = (const u16*)x;
            for (int z = 0; z < 10; z++)
                if (bf(xp[n * 10 + z]) > 0.5f) { sp = z; break; }
        } else {
            const float* xp = (const float*)x;
            for (int z = 0; z < 10; z++)
                if (xp[n * 10 + z] > 0.5f) { sp = z; break; }
        }
        sps = sp;
        species[n] = sp;
    }
    __syncthreads();
    nf[n * 128 + k] = bf(Wemb[sps * 128 + k]) * 0.31622776601683794f; // 1/sqrt(10)
}

// ---------- edge prep: SH + bessel + histogram ----------
__global__ __launch_bounds__(256) void k_prep_edges(const int* eidx, const void* pos,
                                                    float* esh, float* ef, int* hist,
                                                    const int* flag) {
    int e = blockIdx.x * 256 + threadIdx.x;
    int j = eidx[e], i = eidx[N_EDGES + e];
    float vx, vy, vz;
    if (*flag) {
        const u16* p = (const u16*)pos;
        vx = bf(p[j * 3 + 0]) - bf(p[i * 3 + 0]);
        vy = bf(p[j * 3 + 1]) - bf(p[i * 3 + 1]);
        vz = bf(p[j * 3 + 2]) - bf(p[i * 3 + 2]);
    } else {
        const float* p = (const float*)pos;
        vx = p[j * 3 + 0] - p[i * 3 + 0];
        vy = p[j * 3 + 1] - p[i * 3 + 1];
        vz = p[j * 3 + 2] - p[i * 3 + 2];
    }
    float r = sqrtf(vx * vx + vy * vy + vz * vz + 1e-12f);
    float rinv = 1.f / r;
    float X = vx * rinv, Y = vy * rinv, Z = vz * rinv;
    float x2 = X * X, y2 = Y * Y, z2 = Z * Z;
    const float s3 = 1.7320508075688772f, s15 = 3.872983346207417f, s5 = 2.23606797749979f;
    const float s35_8 = 2.091650066335189f, s105 = 10.246950765959598f;
    const float s21_8 = 1.6201851746019651f, s7 = 2.6457513110645907f;
    float Yh[16];
    Yh[0] = 1.f; Yh[1] = s3 * X; Yh[2] = s3 * Y; Yh[3] = s3 * Z;
    Yh[4] = s15 * X * Y; Yh[5] = s15 * Y * Z; Yh[6] = 0.5f * s5 * (3.f * z2 - 1.f);
    Yh[7] = s15 * X * Z; Yh[8] = 0.5f * s15 * (x2 - y2);
    Yh[9] = s35_8 * Y * (3.f * x2 - y2); Yh[10] = s105 * X * Y * Z;
    Yh[11] = s21_8 * Y * (5.f * z2 - 1.f); Yh[12] = 0.5f * s7 * Z * (5.f * z2 - 3.f);
    Yh[13] = s21_8 * X * (5.f * z2 - 1.f); Yh[14] = 0.5f * s105 * Z * (x2 - y2);
    Yh[15] = s35_8 * X * (x2 - 3.f * y2);
#pragma unroll
    for (int m = 0; m < 16; m++) esh[e * 16 + m] = Yh[m];

    float u = r * 0.2f;
    float fc = 0.f;
    if (u < 1.f) {
        float u2 = u * u, u4 = u2 * u2, u5 = u4 * u, u6 = u5 * u, u7 = u6 * u;
        fc = 1.f - 21.f * u5 + 35.f * u6 - 15.f * u7;
    }
    const float pref = 0.6324555320336759f; // sqrt(2/5)
#pragma unroll
    for (int nn = 1; nn <= 8; nn++)
        ef[e * 8 + nn - 1] = pref * sinf((float)nn * 3.14159265358979323846f * u) * rinv * fc;

    atomicAdd(&hist[i], 1);
}

// ---------- exclusive scan of 16384 counts ----------
__global__ __launch_bounds__(1024) void k_scan(const int* hist, int* offs, int* cursor) {
    __shared__ int part[1024];
    int t = threadIdx.x;
    int base = t * 16;
    int v[16]; int s = 0;
#pragma unroll
    for (int q = 0; q < 16; q++) { v[q] = hist[base + q]; s += v[q]; }
    part[t] = s;
    __syncthreads();
    for (int d = 1; d < 1024; d <<= 1) {
        int add = (t >= d) ? part[t - d] : 0;
        __syncthreads();
        part[t] += add;
        __syncthreads();
    }
    int run = part[t] - s; // exclusive
#pragma unroll
    for (int q = 0; q < 16; q++) { offs[base + q] = run; cursor[base + q] = run; run += v[q]; }
    if (t == 1023) offs[16384] = run;
}

// ---------- counting-sort scatter ----------
__global__ __launch_bounds__(256) void k_sort(const int* eidx, int* cursor, int* sorted) {
    int e = blockIdx.x * 256 + threadIdx.x;
    int i = eidx[N_EDGES + e];
    int p = atomicAdd(&cursor[i], 1);
    sorted[p] = e;
}

// ---------- up + skip-connection matvecs (up stored bf16) ----------
__global__ __launch_bounds__(128) void k_up_sc(int t, const float* nf, const int* species,
                                               const u16* Wup, const u16* Wskip,
                                               u16* up, float* sc) {
    int n = blockIdx.x, k = threadIdx.x;
    __shared__ float nfs[128];
    nfs[k] = nf[n * 128 + k];
    __syncthreads();
    int sp = species[n];
    const u16* wu = Wup + (size_t)t * 16384;
    const u16* ws = Wskip + ((size_t)t * 10 + sp) * 16384;
    float au = 0.f, av = 0.f;
#pragma unroll 4
    for (int kk = 0; kk < 128; kk++) {
        float v = nfs[kk];
        au += v * bf(wu[kk * 128 + k]);
        av += v * bf(ws[kk * 128 + k]);
    }
    up[n * 128 + k] = fb(au * 0.08838834764831845f);   // 1/sqrt(128)
    sc[n * 128 + k] = av * 0.027950849718747373f;      // 1/sqrt(1280)
}

// ---------- radial MLP via MFMA: 8 -> 64 -> 64 -> 64 -> 512 ----------
// 64 edges/block, 4 waves x 16 edges. h in A-frag-ready LDS layout (stride 68).
// Wr1T/Wr2T/Wr3T transposed [n][k] => B-fragments are contiguous 16B global loads.
#define HS 68
__global__ __launch_bounds__(256) void k_radial(int t, const float* ef, const u16* Wr0,
                                                const u16* Wr1T, const u16* Wr2T,
                                                const u16* Wr3T, u16* tpw) {
    __shared__ u16 w0s[512];
    __shared__ u16 h[4][2][16 * HS];
    __shared__ u16 st3[4][16 * 136];
    int tid = threadIdx.x;
    const u16* w0p = Wr0 + t * 512;
    if (tid < 128) *(ushort4*)&w0s[tid * 4] = *(const ushort4*)&w0p[tid * 4];
    __syncthreads();

    int wave = tid >> 6, lane = tid & 63;
    int m16 = lane & 15, quad = lane >> 4;
    int E0 = blockIdx.x * 64 + wave * 16;

    // ---- L0 (VALU, K=8) ----
    float efv[8];
    {
        const float* ep = ef + (size_t)(E0 + m16) * 8;
        float4 e0 = *(const float4*)ep, e1 = *(const float4*)(ep + 4);
        efv[0] = e0.x; efv[1] = e0.y; efv[2] = e0.z; efv[3] = e0.w;
        efv[4] = e1.x; efv[5] = e1.y; efv[6] = e1.z; efv[7] = e1.w;
    }
    u16* h0 = h[wave][0];
    u16* h1 = h[wave][1];
#pragma unroll
    for (int o = 0; o < 16; o++) {
        int oc = quad * 16 + o;
        float a = 0.f;
#pragma unroll
        for (int b = 0; b < 8; b++) a += efv[b] * bf(w0s[b * 64 + oc]);
        h0[m16 * HS + oc] = fb(silu_f(a * 0.35355339059327373f));
    }
    __syncthreads();

    // ---- L1 (MFMA 16x16x32, K=64, N=64) ----
    const u16* w1p = Wr1T + t * 4096;
    short8 afr[2];
    afr[0] = *(const short8*)&h0[m16 * HS + quad * 8];
    afr[1] = *(const short8*)&h0[m16 * HS + 32 + quad * 8];
    {
        float4v acc[4];
#pragma unroll
        for (int nt = 0; nt < 4; nt++) {
            acc[nt] = (float4v){0.f, 0.f, 0.f, 0.f};
#pragma unroll
            for (int ks = 0; ks < 2; ks++) {
                short8 bfr = *(const short8*)&w1p[(nt * 16 + m16) * 64 + ks * 32 + quad * 8];
                acc[nt] = __builtin_amdgcn_mfma_f32_16x16x32_bf16(afr[ks], bfr, acc[nt], 0, 0, 0);
            }
        }
#pragma unroll
        for (int nt = 0; nt < 4; nt++)
#pragma unroll
            for (int r = 0; r < 4; r++)
                h1[(quad * 4 + r) * HS + nt * 16 + m16] = fb(silu_f(acc[nt][r] * 0.125f));
    }
    __syncthreads();

    // ---- L2 (MFMA, K=64, N=64) ----
    const u16* w2p = Wr2T + t * 4096;
    afr[0] = *(const short8*)&h1[m16 * HS + quad * 8];
    afr[1] = *(const short8*)&h1[m16 * HS + 32 + quad * 8];
    {
        float4v acc[4];
#pragma unroll
        for (int nt = 0; nt < 4; nt++) {
            acc[nt] = (float4v){0.f, 0.f, 0.f, 0.f};
#pragma unroll
            for (int ks = 0; ks < 2; ks++) {
                short8 bfr = *(const short8*)&w2p[(nt * 16 + m16) * 64 + ks * 32 + quad * 8];
                acc[nt] = __builtin_amdgcn_mfma_f32_16x16x32_bf16(afr[ks], bfr, acc[nt], 0, 0, 0);
            }
        }
#pragma unroll
        for (int nt = 0; nt < 4; nt++)
#pragma unroll
            for (int r = 0; r < 4; r++)
                h0[(quad * 4 + r) * HS + nt * 16 + m16] = fb(silu_f(acc[nt][r] * 0.125f));
    }
    __syncthreads();

    // ---- L3 (MFMA, K=64, N=512), chunked 4x128, repack via LDS, no activation ----
    const u16* w3p = Wr3T + t * 32768;
    afr[0] = *(const short8*)&h0[m16 * HS + quad * 8];
    afr[1] = *(const short8*)&h0[m16 * HS + 32 + quad * 8];
    u16* stw = st3[wave];
    for (int cc = 0; cc < 4; cc++) {
#pragma unroll
        for (int nt8 = 0; nt8 < 8; nt8++) {
            int nt = cc * 8 + nt8;
            float4v a3 = (float4v){0.f, 0.f, 0.f, 0.f};
#pragma unroll
            for (int ks = 0; ks < 2; ks++) {
                short8 bfr = *(const short8*)&w3p[(nt * 16 + m16) * 64 + ks * 32 + quad * 8];
                a3 = __builtin_amdgcn_mfma_f32_16x16x32_bf16(afr[ks], bfr, a3, 0, 0, 0);
            }
#pragma unroll
            for (int r = 0; r < 4; r++)
                stw[(quad * 4 + r) * 136 + nt8 * 16 + m16] = fb(a3[r] * 0.125f);
        }
        __syncthreads();
#pragma unroll
        for (int st = 0; st < 4; st++) {
            int edge = st * 4 + quad;
            uint4 v = *(const uint4*)&stw[edge * 136 + m16 * 8];
            *(uint4*)&tpw[(size_t)(E0 + edge) * 512 + cc * 128 + m16 * 8] = v;
        }
        __syncthreads();
    }
}

// ---------- message accumulation -> l-grouped global msg (bf16) ----------
__global__ __launch_bounds__(256) void k_msg(const int* offs, const int* sorted,
                                             const int* eidx, const float* esh,
                                             const u16* up, const u16* tpw, u16* msgA) {
    const int LM[16] = {0,1,1,1,2,2,2,2,2,3,3,3,3,3,3,3};
    int tid = threadIdx.x;
    int nsub = tid >> 5;
    int kq = tid & 31;
    int k4 = kq * 4;
    int n = blockIdx.x * 8 + nsub;

    float acc[16][4];
#pragma unroll
    for (int m = 0; m < 16; m++)
#pragma unroll
        for (int q = 0; q < 4; q++) acc[m][q] = 0.f;
    int s = offs[n], e1 = offs[n + 1];
    for (int idx = s; idx < e1; idx++) {
        int e = sorted[idx];
        int j = eidx[e];
        ushort4 uu = *(const ushort4*)(up + (size_t)j * 128 + k4);
        float u0 = bf(uu.x), u1 = bf(uu.y), u2 = bf(uu.z), u3 = bf(uu.w);
        float4 sA = *(const float4*)(esh + (size_t)e * 16);
        float4 sB = *(const float4*)(esh + (size_t)e * 16 + 4);
        float4 sC = *(const float4*)(esh + (size_t)e * 16 + 8);
        float4 sD = *(const float4*)(esh + (size_t)e * 16 + 12);
        float sh[16] = {sA.x, sA.y, sA.z, sA.w, sB.x, sB.y, sB.z, sB.w,
                        sC.x, sC.y, sC.z, sC.w, sD.x, sD.y, sD.z, sD.w};
        float p[4][4];
#pragma unroll
        for (int l = 0; l < 4; l++) {
            ushort4 tp = *(const ushort4*)(tpw + (size_t)e * 512 + l * 128 + k4);
            p[l][0] = u0 * bf(tp.x); p[l][1] = u1 * bf(tp.y);
            p[l][2] = u2 * bf(tp.z); p[l][3] = u3 * bf(tp.w);
        }
#pragma unroll
        for (int m = 0; m < 16; m++) {
            int l = LM[m];
            acc[m][0] += sh[m] * p[l][0]; acc[m][1] += sh[m] * p[l][1];
            acc[m][2] += sh[m] * p[l][2]; acc[m][3] += sh[m] * p[l][3];
        }
    }
#pragma unroll
    for (int m = 0; m < 16; m++) {
        int row = RBc[m] + n * RSc[m];
        ushort4 o;
        o.x = fb(acc[m][0] * 0.1f); o.y = fb(acc[m][1] * 0.1f);
        o.z = fb(acc[m][2] * 0.1f); o.w = fb(acc[m][3] * 0.1f);
        *(ushort4*)(msgA + (size_t)row * 128 + k4) = o;
    }
}

// ---------- A = msg @ W_lin[l] / sqrt(128): MFMA GEMM, in-place over msgA ----------
__global__ __launch_bounds__(256) void k_gemmA(int t, u16* msgA, const u16* WlinT) {
    __shared__ u16 wfr[16384];
    int b = blockIdx.x;
    int l, rb0;
    if (b < 256)       { l = 0; rb0 = b * 64; }
    else if (b < 1024) { l = 1; rb0 = 16384  + (b - 256)  * 64; }
    else if (b < 2304) { l = 2; rb0 = 65536  + (b - 1024) * 64; }
    else               { l = 3; rb0 = 147456 + (b - 2304) * 64; }
    int tid = threadIdx.x;
    const u16* wg = WlinT + ((size_t)t * 4 + l) * 16384;
#pragma unroll
    for (int p = 0; p < 8; p++) {
        int slot = p * 256 + tid;
        int nt = slot >> 8, ks = (slot >> 6) & 3, ln = slot & 63;
        int nn = nt * 16 + (ln & 15), k0 = ks * 32 + (ln >> 4) * 8;
        *(uint4*)&wfr[slot * 8] = *(const uint4*)&wg[nn * 128 + k0];
    }
    __syncthreads();

    int wave = tid >> 6, lane = tid & 63;
    int m16 = lane & 15, quad = lane >> 4;
    int rowa = rb0 + wave * 16 + m16;
    const u16* ap = msgA + (size_t)rowa * 128 + quad * 8;
    short8 afr[4];
#pragma unroll
    for (int ks = 0; ks < 4; ks++) afr[ks] = *(const short8*)(ap + ks * 32);

    float4v acc[8];
#pragma unroll
    for (int nt = 0; nt < 8; nt++) acc[nt] = (float4v){0.f, 0.f, 0.f, 0.f};
#pragma unroll
    for (int nt = 0; nt < 8; nt++)
#pragma unroll
        for (int ks = 0; ks < 4; ks++) {
            short8 bfr = *(const short8*)&wfr[((nt * 4 + ks) * 64 + lane) * 8];
            acc[nt] = __builtin_amdgcn_mfma_f32_16x16x32_bf16(afr[ks], bfr, acc[nt], 0, 0, 0);
        }

    const float sAc = 0.08838834764831845f;
    int rowc = rb0 + wave * 16 + quad * 4;
#pragma unroll
    for (int nt = 0; nt < 8; nt++)
#pragma unroll
        for (int r = 0; r < 4; r++)
            msgA[(size_t)(rowc + r) * 128 + nt * 16 + m16] = fb(acc[nt][r] * sAc);
}

// ---------- invariants + product basis + prodlin + skip ----------
__global__ __launch_bounds__(128) void k_bprod(int t, const u16* Ag, const int* species,
                                               const u16* Wp1, const u16* Wp2, const u16* Wp3,
                                               const u16* Wpl, const float* sc, float* nf) {
    const int LM[16] = {0,1,1,1,2,2,2,2,2,3,3,3,3,3,3,3};
    int n = blockIdx.x, k = threadIdx.x;
    int sp = species[n];
    float Am[16];
#pragma unroll
    for (int m = 0; m < 16; m++)
        Am[m] = bf(Ag[(size_t)(RBc[m] + n * RSc[m]) * 128 + k]);
    float A0 = Am[0];
    float inv2[4] = {0.f, 0.f, 0.f, 0.f};
#pragma unroll
    for (int m = 0; m < 16; m++) inv2[LM[m]] += Am[m] * Am[m];
    float w1 = bf(Wp1[((size_t)t * 10 + sp) * 128 + k]);
    float s2 = 0.f, s3v = 0.f;
#pragma unroll
    for (int l = 0; l < 4; l++) {
        float w2 = bf(Wp2[(((size_t)t * 10 + sp) * 4 + l) * 128 + k]);
        float w3 = bf(Wp3[(((size_t)t * 10 + sp) * 4 + l) * 128 + k]);
        s2 += w2 * inv2[l];
        s3v += w3 * inv2[l];
    }
    float b = w1 * A0 + s2 + s3v * A0;
    __shared__ float bs[128];
    bs[k] = b;
    __syncthreads();
    const u16* wp = Wpl + (size_t)t * 16384;
    float acc = 0.f;
#pragma unroll 4
    for (int kk = 0; kk < 128; kk++) acc += bs[kk] * bf(wp[kk * 128 + k]);
    nf[n * 128 + k] = acc * 0.08838834764831845f + sc[n * 128 + k];
}

// ---------- graph readout ----------
__global__ __launch_bounds__(128) void k_reduce(const float* nf, const int* batch,
                                                float* env, float* cnt) {
    int k = threadIdx.x;
    int n0 = blockIdx.x * 128;
    float run = 0.f;
    int gp = batch[n0];
    for (int nn = 0; nn < 128; nn++) {
        int n = n0 + nn;
        int g = batch[n];
        if (g != gp) { atomicAdd(&env[gp * 128 + k], run); run = 0.f; gp = g; }
        run += nf[n * 128 + k];
    }
    atomicAdd(&env[gp * 128 + k], run);
    if (k == 0) {
        float c = 0.f;
        int g2 = batch[n0];
        for (int nn = 0; nn < 128; nn++) {
            int g = batch[n0 + nn];
            if (g != g2) { atomicAdd(&cnt[g2], c); c = 0.f; g2 = g; }
            c += 1.f;
        }
        atomicAdd(&cnt[g2], c);
    }
}

// ---------- final: output float32 ----------
__global__ void k_final(const float* env, const float* cnt, float* out) {
    int i = blockIdx.x * 256 + threadIdx.x;
    if (i < N_GRAPHS * 128) out[i] = env[i] / fmaxf(cnt[i >> 7], 1.f);
}

// ---------- launch ----------
extern "C" void kernel_launch(void* const* d_in, const int* in_sizes, int n_in,
                              void* d_out, int out_size, void* d_ws, size_t ws_size,
                              hipStream_t stream) {
    (void)in_sizes; (void)n_in; (void)out_size; (void)ws_size;
    const void* x    = d_in[0];
    const void* pos  = d_in[1];
    const int* eidx  = (const int*)d_in[14];
    const int* batch = (const int*)d_in[15];

    char* base = (char*)d_ws;
    size_t cur = 0;
    auto alloc = [&](size_t bytes) -> void* {
        void* p = base + cur;
        cur = (cur + bytes + 255) & ~(size_t)255;
        return p;
    };
    int*   flag    = (int*)alloc(4);
    u16*   cvt     = (u16*)alloc((size_t)631552 * 2);
    int*   species = (int*)alloc((size_t)N_NODES * 4);
    int*   hist    = (int*)alloc((size_t)N_NODES * 4);
    int*   offs    = (int*)alloc((size_t)(N_NODES + 1) * 4);
    int*   cursor  = (int*)alloc((size_t)N_NODES * 4);
    int*   sorted  = (int*)alloc((size_t)N_EDGES * 4);
    float* env     = (float*)alloc((size_t)N_GRAPHS * 128 * 4);
    float* cnt     = (float*)alloc((size_t)N_GRAPHS * 4);
    float* nf      = (float*)alloc((size_t)N_NODES * 128 * 4);
    u16*   up      = (u16*)alloc((size_t)N_NODES * 128 * 2);
    float* sc      = (float*)alloc((size_t)N_NODES * 128 * 4);
    float* ef      = (float*)alloc((size_t)N_EDGES * 8 * 4);
    float* esh     = (float*)alloc((size_t)N_EDGES * 16 * 4);
    u16*   tpw     = (u16*)alloc((size_t)N_EDGES * 512 * 2);
    u16*   msgA    = (u16*)alloc((size_t)262144 * 128 * 2);

    static const int cn[12] = {1280, 32768, 1024, 8192, 8192, 65536,
                               131072, 327680, 2560, 10240, 10240, 32768};
    CvtArgs ca;
    size_t off[13]; off[0] = 0;
    for (int q = 0; q < 12; q++) { ca.src[q] = d_in[2 + q]; ca.n[q] = cn[q]; off[q + 1] = off[q] + cn[q]; }
    u16* cWemb  = cvt + off[0];
    u16* cWup   = cvt + off[1];
    u16* cWr0   = cvt + off[2];
    u16* cWr1T  = cvt + off[3];   // transposed [t][n][k]
    u16* cWr2T  = cvt + off[4];   // transposed [t][n][k]
    u16* cWr3T  = cvt + off[5];   // transposed [t][n][k]
    u16* cWlinT = cvt + off[6];   // transposed [t][l][n][kk]
    u16* cWskip = cvt + off[7];
    u16* cWp1   = cvt + off[8];
    u16* cWp2   = cvt + off[9];
    u16* cWp3   = cvt + off[10];
    u16* cWpl   = cvt + off[11];

    k_detect<<<1, 256, 0, stream>>>(x, flag);
    k_convert<<<256, 256, 0, stream>>>(ca, cvt, flag);
    k_zero<<<64, 256, 0, stream>>>((float*)hist, N_NODES);
    k_zero<<<32, 256, 0, stream>>>(env, N_GRAPHS * 128);
    k_zero<<<1, 256, 0, stream>>>(cnt, N_GRAPHS);
    k_prep_nodes<<<N_NODES, 128, 0, stream>>>(x, cWemb, nf, species, flag);
    k_prep_edges<<<N_EDGES / 256, 256, 0, stream>>>(eidx, pos, esh, ef, hist, flag);
    k_scan<<<1, 1024, 0, stream>>>(hist, offs, cursor);
    k_sort<<<N_EDGES / 256, 256, 0, stream>>>(eidx, cursor, sorted);

    for (int t = 0; t < 2; t++) {
        k_up_sc<<<N_NODES, 128, 0, stream>>>(t, nf, species, cWup, cWskip, up, sc);
        k_radial<<<N_EDGES / 64, 256, 0, stream>>>(t, ef, cWr0, cWr1T, cWr2T, cWr3T, tpw);
        k_msg<<<N_NODES / 8, 256, 0, stream>>>(offs, sorted, eidx, esh, up, tpw, msgA);
        k_gemmA<<<4096, 256, 0, stream>>>(t, msgA, cWlinT);
        k_bprod<<<N_NODES, 128, 0, stream>>>(t, msgA, species, cWp1, cWp2, cWp3, cWpl, sc, nf);
    }
    k_reduce<<<N_NODES / 128, 128, 0, stream>>>(nf, batch, env, cnt);
    k_final<<<32, 256, 0, stream>>>(env, cnt, (float*)d_out);
}